// Round 11
// baseline (1424.188 us; speedup 1.0000x reference)
//
#include <hip/hip_runtime.h>
#include <stdint.h>

#define NODES 50000
#define EDGES 800000
#define EMB   256
#define MPAD  50048   // 391*128
#define BNEPS 1e-5f
#define SCANB 196     // 196*256 = 50176 >= NODES

typedef unsigned short u16;
typedef unsigned int   u32;
typedef _Float16 f16;
typedef __attribute__((ext_vector_type(4))) _Float16 f16x4;
typedef __attribute__((ext_vector_type(8))) _Float16 f16x8;
typedef __attribute__((ext_vector_type(4))) float f32x4;

// ---------------- setup kernels ----------------

__global__ void k_w1t(const float* __restrict__ W1, f16* __restrict__ Wt){
  int i = blockIdx.x * 256 + threadIdx.x;          // 5*512*256, dst layout [l][n][k]
  if (i >= 5*512*256) return;
  int k = i & 255, n = (i >> 8) & 511, l = i >> 17;
  Wt[i] = (f16)W1[((size_t)l << 17) + ((size_t)k << 9) + n];
}
__global__ void k_w2t(const float* __restrict__ W2, f16* __restrict__ Wt){
  int i = blockIdx.x * 256 + threadIdx.x;          // 5*256*512, dst layout [l][n][k]
  if (i >= 5*256*512) return;
  int k = i & 511, n = (i >> 9) & 255, l = i >> 17;
  Wt[i] = (f16)W2[((size_t)l << 17) + ((size_t)k << 8) + n];
}

__global__ void k_ebond(const float* __restrict__ bemb, f16* __restrict__ eb){
  int l = blockIdx.x / 216, p = blockIdx.x % 216;
  int a0 = p % 6, a1 = (p / 6) % 6, a2 = p / 36;
  int d0 = threadIdx.x * 4;
  const float* b = bemb + (size_t)l * 3 * 6 * 256;
  float4 v0 = *(const float4*)(b + (0*6 + a0)*256 + d0);
  float4 v1 = *(const float4*)(b + (1*6 + a1)*256 + d0);
  float4 v2 = *(const float4*)(b + (2*6 + a2)*256 + d0);
  f16x4 o = {(f16)(v0.x+v1.x+v2.x), (f16)(v0.y+v1.y+v2.y),
             (f16)(v0.z+v1.z+v2.z), (f16)(v0.w+v1.w+v2.w)};
  *(f16x4*)(eb + (((size_t)l*216 + p) << 8) + d0) = o;
}

__global__ void k_atom(const int* __restrict__ x, const float* __restrict__ aemb,
                       f16* __restrict__ h){
  int n = blockIdx.x * 4 + (threadIdx.x >> 6);
  int lane = threadIdx.x & 63;
  if (n >= NODES) return;
  int d0 = lane * 4;
  float a0=0.f, a1=0.f, a2=0.f, a3=0.f;
#pragma unroll
  for (int f = 0; f < 9; ++f){
    int v = x[n*9 + f];
    float4 e = *(const float4*)(aemb + (((size_t)f*120 + v) << 8) + d0);
    a0 += e.x; a1 += e.y; a2 += e.z; a3 += e.w;
  }
  f16x4 o = {(f16)a0, (f16)a1, (f16)a2, (f16)a3};
  *(f16x4*)(h + (size_t)n*EMB + d0) = o;
}

// ---------------- CSR build ----------------

__global__ void k_hist(const int* __restrict__ dst, int* __restrict__ counts){
  int e = blockIdx.x * 256 + threadIdx.x;
  if (e < EDGES) atomicAdd(&counts[dst[e]], 1);
}

__global__ void k_bsum(const int* __restrict__ counts, int* __restrict__ bsums){
  __shared__ int red[256];
  int t = threadIdx.x;
  int i = blockIdx.x * 256 + t;
  red[t] = (i < NODES) ? counts[i] : 0;
  __syncthreads();
  for (int off = 128; off > 0; off >>= 1){
    if (t < off) red[t] += red[t + off];
    __syncthreads();
  }
  if (t == 0) bsums[blockIdx.x] = red[0];
}

__global__ void k_bscan(int* __restrict__ bsums){
  __shared__ int sc[256];
  int t = threadIdx.x;
  int v = (t < SCANB) ? bsums[t] : 0;
  sc[t] = v;
  __syncthreads();
  for (int off = 1; off < 256; off <<= 1){
    int u = (t >= off) ? sc[t - off] : 0;
    __syncthreads();
    sc[t] += u;
    __syncthreads();
  }
  if (t < SCANB) bsums[t] = sc[t] - v;              // exclusive
}

__global__ void k_fill(const int* __restrict__ counts, const int* __restrict__ bsums,
                       int* __restrict__ rs, int* __restrict__ fill){
  __shared__ int sc[256];
  int t = threadIdx.x;
  int i = blockIdx.x * 256 + t;
  int v = (i < NODES) ? counts[i] : 0;
  sc[t] = v;
  __syncthreads();
  for (int off = 1; off < 256; off <<= 1){
    int u = (t >= off) ? sc[t - off] : 0;
    __syncthreads();
    sc[t] += u;
    __syncthreads();
  }
  if (i < NODES){
    int e = bsums[blockIdx.x] + sc[t] - v;          // exclusive prefix
    rs[i] = e; fill[i] = e;
    if (i == NODES - 1) rs[NODES] = e + v;
  }
}

__global__ void k_scatter(const int* __restrict__ src, const int* __restrict__ dst,
                          const int* __restrict__ ea, int* __restrict__ fill,
                          int* __restrict__ csrc, int* __restrict__ cattr){
  int e = blockIdx.x * 256 + threadIdx.x;
  if (e >= EDGES) return;
  int d = dst[e];
  int p = atomicAdd(&fill[d], 1);
  csrc[p]  = src[e];
  cattr[p] = ea[e*3+0] + 6*ea[e*3+1] + 36*ea[e*3+2];
}

// ---------------- per-layer kernels ----------------

// One wave per node. Half-wave edge pairing + index software pipeline.
__global__ void k_gather(const f16* __restrict__ h, const f16* __restrict__ ebl,
                         const int* __restrict__ rs, const int* __restrict__ csrc,
                         const int* __restrict__ cattr, const float* __restrict__ epsv,
                         int layer, f16* __restrict__ z){
  int n = blockIdx.x * 4 + (threadIdx.x >> 6);
  int lane = threadIdx.x & 63;
  int half = lane >> 5;
  int dl = (lane & 31) * 8;
  if (n >= MPAD) return;
  if (n >= NODES){
    if (half == 0){
      f16x8 zz = {(f16)0.f,(f16)0.f,(f16)0.f,(f16)0.f,(f16)0.f,(f16)0.f,(f16)0.f,(f16)0.f};
      *(f16x8*)(z + (size_t)n*EMB + dl) = zz;
    }
    return;
  }
  float acc[8];
#pragma unroll
  for (int k = 0; k < 8; ++k) acc[k] = 0.f;
  int i1 = rs[n+1];
  int i  = rs[n] + half;
  bool v = i < i1;
  int s = 0, pa = 0;
  if (v){ s = csrc[i]; pa = cattr[i]; }
  while (v){
    f16x8 hv = *(const f16x8*)(h + (size_t)s*EMB + dl);
    f16x8 ev = *(const f16x8*)(ebl + ((size_t)pa << 8) + dl);
    int in = i + 2;
    bool vn = in < i1;
    int sn = 0, pan = 0;
    if (vn){ sn = csrc[in]; pan = cattr[in]; }     // overlap with hv/ev latency
#pragma unroll
    for (int k = 0; k < 8; ++k)
      acc[k] += fmaxf((float)hv[k] + (float)ev[k], 0.f);
    i = in; s = sn; pa = pan; v = vn;
  }
#pragma unroll
  for (int k = 0; k < 8; ++k) acc[k] += __shfl_xor(acc[k], 32);
  if (half == 0){
    float ep = 1.0f + epsv[layer];
    f16x8 hv = *(const f16x8*)(h + (size_t)n*EMB + dl);
    f16x8 o;
#pragma unroll
    for (int k = 0; k < 8; ++k) o[k] = (f16)(acc[k] + ep*(float)hv[k]);
    *(f16x8*)(z + (size_t)n*EMB + dl) = o;
  }
}

// Barrier-free GEMM: A [M x K] f16 row-major, Bt [NCOL x K] f16 (pre-transposed).
// Fragments loaded straight from global (L2/LLC-hot) into registers; no LDS.
// FUSEBN: A is pre-BN hidden; apply y = relu(a*sc+sh) in-register (f16 packed),
// zeroing pad rows (row >= NODES) so BN stats of the NEXT stage stay exact.
// C f16 pre-BN; column sum/sumsq accumulated via f32 atomics.
template<int K, int NCOL, bool FUSEBN>
__global__ __launch_bounds__(256)
void k_gemm(const f16* __restrict__ A, const f16* __restrict__ Bt,
            const f16* __restrict__ bnsc, const f16* __restrict__ bnsh,
            f16* __restrict__ C, float* __restrict__ csum, float* __restrict__ csq){
  const int tid  = threadIdx.x;
  const int lane = tid & 63;
  const int wid  = tid >> 6;
  const int bm0 = blockIdx.x * 128;
  const int bn0 = blockIdx.y * 128;
  const int wm = (wid >> 1) * 64;
  const int wn = (wid & 1) * 64;
  const int lr = lane & 15;          // fragment row within 16
  const int kc = (lane >> 4) * 8;    // k sub-chunk offset within 32

  const f16* Ap = A  + (size_t)(bm0 + wm + lr)*K + kc;
  const f16* Bp = Bt + (size_t)(bn0 + wn + lr)*K + kc;

  f32x4 acc[4][4];
#pragma unroll
  for (int m = 0; m < 4; ++m)
#pragma unroll
    for (int n = 0; n < 4; ++n) acc[m][n] = (f32x4){0.f,0.f,0.f,0.f};

  const f16x8 zero8 = {(f16)0.f,(f16)0.f,(f16)0.f,(f16)0.f,
                       (f16)0.f,(f16)0.f,(f16)0.f,(f16)0.f};

#pragma unroll 2
  for (int kk = 0; kk < K/32; ++kk){
    f16x8 af[4], bf[4];
#pragma unroll
    for (int m = 0; m < 4; ++m)
      af[m] = *(const f16x8*)(Ap + (size_t)m*16*K + kk*32);
#pragma unroll
    for (int n = 0; n < 4; ++n)
      bf[n] = *(const f16x8*)(Bp + (size_t)n*16*K + kk*32);
    if (FUSEBN){
      f16x8 sc = *(const f16x8*)(bnsc + kk*32 + kc);
      f16x8 sh = *(const f16x8*)(bnsh + kk*32 + kc);
#pragma unroll
      for (int m = 0; m < 4; ++m){
        f16x8 t = af[m]*sc + sh;
#pragma unroll
        for (int j = 0; j < 8; ++j) t[j] = (t[j] > (f16)0.f) ? t[j] : (f16)0.f;
        af[m] = (bm0 + wm + m*16 + lr < NODES) ? t : zero8;
      }
    }
#pragma unroll
    for (int m = 0; m < 4; ++m)
#pragma unroll
      for (int n = 0; n < 4; ++n)
        acc[m][n] = __builtin_amdgcn_mfma_f32_16x16x32_f16(af[m], bf[n], acc[m][n], 0, 0, 0);
  }

  const int r0 = (lane >> 4) * 4;
  const int cc = lane & 15;
#pragma unroll
  for (int m = 0; m < 4; ++m)
#pragma unroll
    for (int n = 0; n < 4; ++n)
#pragma unroll
      for (int j = 0; j < 4; ++j){
        int row = bm0 + wm + m*16 + r0 + j;
        int col = bn0 + wn + n*16 + cc;
        C[(size_t)row*NCOL + col] = (f16)acc[m][n][j];
      }
#pragma unroll
  for (int n = 0; n < 4; ++n){
    float s = 0.f, q = 0.f;
#pragma unroll
    for (int m = 0; m < 4; ++m)
#pragma unroll
      for (int j = 0; j < 4; ++j){ float v = acc[m][n][j]; s += v; q += v*v; }
    s += __shfl_xor(s, 16); q += __shfl_xor(q, 16);
    s += __shfl_xor(s, 32); q += __shfl_xor(q, 32);
    if (lane < 16){
      atomicAdd(csum + bn0 + wn + n*16 + cc, s);
      atomicAdd(csq  + bn0 + wn + n*16 + cc, q);
    }
  }
}

__global__ void k_finalize(const float* __restrict__ sum, const float* __restrict__ sumsq,
                           const float* __restrict__ g, const float* __restrict__ be,
                           float* __restrict__ scale, float* __restrict__ shift,
                           f16* __restrict__ scf, f16* __restrict__ shf, int nc){
  int c = blockIdx.x * 256 + threadIdx.x;
  if (c >= nc) return;
  float m = sum[c] * (1.0f / NODES);
  float v = sumsq[c] * (1.0f / NODES) - m*m;
  float sc = rsqrtf(v + BNEPS) * g[c];
  float sh = be[c] - m*sc;
  scale[c] = sc;  shift[c] = sh;
  scf[c] = (f16)sc;  shf[c] = (f16)sh;
}

__global__ void k_apply2(const f16* __restrict__ zp, const float* __restrict__ scale,
                         const float* __restrict__ shift, f16* __restrict__ hout,
                         float* __restrict__ fout, int dorelu){
  int idx = blockIdx.x * 256 + threadIdx.x;       // 8 elems each, NODES*256 total
  int row = idx >> 5;
  int c0  = (idx & 31) * 8;
  if (row >= NODES) return;
  size_t off = (size_t)row * EMB + c0;
  f16x8 v = *(const f16x8*)(zp + off);
  float4 sA = *(const float4*)(scale + c0), sB = *(const float4*)(scale + c0 + 4);
  float4 tA = *(const float4*)(shift + c0), tB = *(const float4*)(shift + c0 + 4);
  float r0 = (float)v[0]*sA.x + tA.x;
  float r1 = (float)v[1]*sA.y + tA.y;
  float r2 = (float)v[2]*sA.z + tA.z;
  float r3 = (float)v[3]*sA.w + tA.w;
  float r4 = (float)v[4]*sB.x + tB.x;
  float r5 = (float)v[5]*sB.y + tB.y;
  float r6 = (float)v[6]*sB.z + tB.z;
  float r7 = (float)v[7]*sB.w + tB.w;
  if (dorelu){
    r0=fmaxf(r0,0.f); r1=fmaxf(r1,0.f); r2=fmaxf(r2,0.f); r3=fmaxf(r3,0.f);
    r4=fmaxf(r4,0.f); r5=fmaxf(r5,0.f); r6=fmaxf(r6,0.f); r7=fmaxf(r7,0.f);
  }
  if (fout){
    float4 f0 = {r0,r1,r2,r3}, f1 = {r4,r5,r6,r7};
    float* q = fout + off;
    *(float4*)q = f0; *(float4*)(q + 4) = f1;
  } else {
    f16x8 o = {(f16)r0,(f16)r1,(f16)r2,(f16)r3,(f16)r4,(f16)r5,(f16)r6,(f16)r7};
    *(f16x8*)(hout + off) = o;
  }
}

// ---------------- launch ----------------

extern "C" void kernel_launch(void* const* d_in, const int* in_sizes, int n_in,
                              void* d_out, int out_size, void* d_ws, size_t ws_size,
                              hipStream_t stream){
  const int*   x    = (const int*)  d_in[0];
  const int*   ei   = (const int*)  d_in[1];
  const int*   ea   = (const int*)  d_in[2];
  const float* aemb = (const float*)d_in[3];
  const float* bemb = (const float*)d_in[4];
  const float* epsv = (const float*)d_in[5];
  const float* W1   = (const float*)d_in[6];
  const float* g1   = (const float*)d_in[8];
  const float* be1  = (const float*)d_in[9];
  const float* W2   = (const float*)d_in[10];
  const float* g2   = (const float*)d_in[12];
  const float* be2  = (const float*)d_in[13];
  float* out = (float*)d_out;

  char* p = (char*)d_ws;
  auto take = [&](size_t bytes){ char* r = p; p += (bytes + 255) & ~(size_t)255; return r; };
  f16* h      = (f16*)take((size_t)NODES*EMB*2);
  f16* z      = (f16*)take((size_t)MPAD*EMB*2);     // reused as GEMM2 output
  f16* hidden = (f16*)take((size_t)MPAD*512*2);
  f16* W1t    = (f16*)take((size_t)5*512*256*2);
  f16* W2t    = (f16*)take((size_t)5*256*512*2);
  f16* eb     = (f16*)take((size_t)5*216*256*2);
  float* stats= (float*)take((size_t)4*512*4);
  float* csum = stats, *csq = stats + 512, *scale = stats + 1024, *shift = stats + 1536;
  f16* scf    = (f16*)take((size_t)512*2);
  f16* shf    = (f16*)take((size_t)512*2);
  int* counts = (int*)take((size_t)NODES*4);
  int* rs     = (int*)take((size_t)(NODES+1)*4);
  int* fill   = (int*)take((size_t)NODES*4);
  int* bsums  = (int*)take((size_t)SCANB*4);
  int* csrc   = (int*)take((size_t)EDGES*4);
  int* cattr  = (int*)take((size_t)EDGES*4);

  k_w1t<<<2560, 256, 0, stream>>>(W1, W1t);
  k_w2t<<<2560, 256, 0, stream>>>(W2, W2t);
  k_ebond<<<5*216, 64, 0, stream>>>(bemb, eb);
  k_atom<<<12500, 256, 0, stream>>>(x, aemb, h);
  hipMemsetAsync(counts, 0, (size_t)NODES*4, stream);
  k_hist<<<EDGES/256, 256, 0, stream>>>(ei + EDGES, counts);
  k_bsum<<<SCANB, 256, 0, stream>>>(counts, bsums);
  k_bscan<<<1, 256, 0, stream>>>(bsums);
  k_fill<<<SCANB, 256, 0, stream>>>(counts, bsums, rs, fill);
  k_scatter<<<EDGES/256, 256, 0, stream>>>(ei, ei + EDGES, ea, fill, csrc, cattr);

  for (int l = 0; l < 5; ++l){
    k_gather<<<MPAD/4, 256, 0, stream>>>(h, eb + (size_t)l*216*256, rs, csrc, cattr, epsv, l, z);
    hipMemsetAsync(stats, 0, 2*512*4, stream);
    k_gemm<256,512,false><<<dim3(MPAD/128, 4), 256, 0, stream>>>(
        z, W1t + (size_t)l*512*256, nullptr, nullptr, hidden, csum, csq);
    k_finalize<<<2, 256, 0, stream>>>(csum, csq, g1 + l*512, be1 + l*512,
                                      scale, shift, scf, shf, 512);
    hipMemsetAsync(stats, 0, 2*512*4, stream);
    k_gemm<512,256,true><<<dim3(MPAD/128, 2), 256, 0, stream>>>(
        hidden, W2t + (size_t)l*256*512, scf, shf, z, csum, csq);
    k_finalize<<<1, 256, 0, stream>>>(csum, csq, g2 + l*256, be2 + l*256,
                                      scale, shift, scf, shf, 256);
    if (l < 4)
      k_apply2<<<NODES*32/256, 256, 0, stream>>>(z, scale, shift, h, nullptr, 1);
    else
      k_apply2<<<NODES*32/256, 256, 0, stream>>>(z, scale, shift, nullptr, out, 0);
  }
}

// Round 12
// 1187.814 us; speedup vs baseline: 1.1990x; 1.1990x over previous
//
#include <hip/hip_runtime.h>
#include <stdint.h>

#define NODES 50000
#define EDGES 800000
#define EMB   256
#define MPAD  50048   // 391*128
#define BNEPS 1e-5f
#define SCANB 196     // 196*256 = 50176 >= NODES

typedef unsigned short u16;
typedef unsigned int   u32;
typedef _Float16 f16;
typedef __attribute__((ext_vector_type(4))) _Float16 f16x4;
typedef __attribute__((ext_vector_type(8))) _Float16 f16x8;
typedef __attribute__((ext_vector_type(4))) float f32x4;

__device__ __forceinline__ void gload16(const void* g, void* l){
  __builtin_amdgcn_global_load_lds((const __attribute__((address_space(1))) void*)g,
                                   (__attribute__((address_space(3))) void*)l, 16, 0, 0);
}

// ---------------- setup kernels ----------------

__global__ void k_w1t(const float* __restrict__ W1, f16* __restrict__ Wt){
  int i = blockIdx.x * 256 + threadIdx.x;          // 5*512*256, dst layout [l][n][k]
  if (i >= 5*512*256) return;
  int k = i & 255, n = (i >> 8) & 511, l = i >> 17;
  Wt[i] = (f16)W1[((size_t)l << 17) + ((size_t)k << 9) + n];
}
__global__ void k_w2t(const float* __restrict__ W2, f16* __restrict__ Wt){
  int i = blockIdx.x * 256 + threadIdx.x;          // 5*256*512, dst layout [l][n][k]
  if (i >= 5*256*512) return;
  int k = i & 511, n = (i >> 9) & 255, l = i >> 17;
  Wt[i] = (f16)W2[((size_t)l << 17) + ((size_t)k << 8) + n];
}

__global__ void k_ebond(const float* __restrict__ bemb, f16* __restrict__ eb){
  int l = blockIdx.x / 216, p = blockIdx.x % 216;
  int a0 = p % 6, a1 = (p / 6) % 6, a2 = p / 36;
  int d0 = threadIdx.x * 4;
  const float* b = bemb + (size_t)l * 3 * 6 * 256;
  float4 v0 = *(const float4*)(b + (0*6 + a0)*256 + d0);
  float4 v1 = *(const float4*)(b + (1*6 + a1)*256 + d0);
  float4 v2 = *(const float4*)(b + (2*6 + a2)*256 + d0);
  f16x4 o = {(f16)(v0.x+v1.x+v2.x), (f16)(v0.y+v1.y+v2.y),
             (f16)(v0.z+v1.z+v2.z), (f16)(v0.w+v1.w+v2.w)};
  *(f16x4*)(eb + (((size_t)l*216 + p) << 8) + d0) = o;
}

__global__ void k_atom(const int* __restrict__ x, const float* __restrict__ aemb,
                       f16* __restrict__ h){
  int n = blockIdx.x * 4 + (threadIdx.x >> 6);
  int lane = threadIdx.x & 63;
  if (n >= NODES) return;
  int d0 = lane * 4;
  float a0=0.f, a1=0.f, a2=0.f, a3=0.f;
#pragma unroll
  for (int f = 0; f < 9; ++f){
    int v = x[n*9 + f];
    float4 e = *(const float4*)(aemb + (((size_t)f*120 + v) << 8) + d0);
    a0 += e.x; a1 += e.y; a2 += e.z; a3 += e.w;
  }
  f16x4 o = {(f16)a0, (f16)a1, (f16)a2, (f16)a3};
  *(f16x4*)(h + (size_t)n*EMB + d0) = o;
}

// ---------------- CSR build ----------------

__global__ void k_hist(const int* __restrict__ dst, int* __restrict__ counts){
  int e = blockIdx.x * 256 + threadIdx.x;
  if (e < EDGES) atomicAdd(&counts[dst[e]], 1);
}

__global__ void k_bsum(const int* __restrict__ counts, int* __restrict__ bsums){
  __shared__ int red[256];
  int t = threadIdx.x;
  int i = blockIdx.x * 256 + t;
  red[t] = (i < NODES) ? counts[i] : 0;
  __syncthreads();
  for (int off = 128; off > 0; off >>= 1){
    if (t < off) red[t] += red[t + off];
    __syncthreads();
  }
  if (t == 0) bsums[blockIdx.x] = red[0];
}

__global__ void k_bscan(int* __restrict__ bsums){
  __shared__ int sc[256];
  int t = threadIdx.x;
  int v = (t < SCANB) ? bsums[t] : 0;
  sc[t] = v;
  __syncthreads();
  for (int off = 1; off < 256; off <<= 1){
    int u = (t >= off) ? sc[t - off] : 0;
    __syncthreads();
    sc[t] += u;
    __syncthreads();
  }
  if (t < SCANB) bsums[t] = sc[t] - v;              // exclusive
}

__global__ void k_fill(const int* __restrict__ counts, const int* __restrict__ bsums,
                       int* __restrict__ rs, int* __restrict__ fill){
  __shared__ int sc[256];
  int t = threadIdx.x;
  int i = blockIdx.x * 256 + t;
  int v = (i < NODES) ? counts[i] : 0;
  sc[t] = v;
  __syncthreads();
  for (int off = 1; off < 256; off <<= 1){
    int u = (t >= off) ? sc[t - off] : 0;
    __syncthreads();
    sc[t] += u;
    __syncthreads();
  }
  if (i < NODES){
    int e = bsums[blockIdx.x] + sc[t] - v;          // exclusive prefix
    rs[i] = e; fill[i] = e;
    if (i == NODES - 1) rs[NODES] = e + v;
  }
}

__global__ void k_scatter(const int* __restrict__ src, const int* __restrict__ dst,
                          const int* __restrict__ ea, int* __restrict__ fill,
                          int* __restrict__ csrc, int* __restrict__ cattr){
  int e = blockIdx.x * 256 + threadIdx.x;
  if (e >= EDGES) return;
  int d = dst[e];
  int p = atomicAdd(&fill[d], 1);
  csrc[p]  = src[e];
  cattr[p] = ea[e*3+0] + 6*ea[e*3+1] + 36*ea[e*3+2];
}

// ---------------- per-layer kernels ----------------

// One wave per node. Half-wave edge pairing + index software pipeline.
__global__ void k_gather(const f16* __restrict__ h, const f16* __restrict__ ebl,
                         const int* __restrict__ rs, const int* __restrict__ csrc,
                         const int* __restrict__ cattr, const float* __restrict__ epsv,
                         int layer, f16* __restrict__ z){
  int n = blockIdx.x * 4 + (threadIdx.x >> 6);
  int lane = threadIdx.x & 63;
  int half = lane >> 5;
  int dl = (lane & 31) * 8;
  if (n >= MPAD) return;
  if (n >= NODES){
    if (half == 0){
      f16x8 zz = {(f16)0.f,(f16)0.f,(f16)0.f,(f16)0.f,(f16)0.f,(f16)0.f,(f16)0.f,(f16)0.f};
      *(f16x8*)(z + (size_t)n*EMB + dl) = zz;
    }
    return;
  }
  float acc[8];
#pragma unroll
  for (int k = 0; k < 8; ++k) acc[k] = 0.f;
  int i1 = rs[n+1];
  int i  = rs[n] + half;
  bool v = i < i1;
  int s = 0, pa = 0;
  if (v){ s = csrc[i]; pa = cattr[i]; }
  while (v){
    f16x8 hv = *(const f16x8*)(h + (size_t)s*EMB + dl);
    f16x8 ev = *(const f16x8*)(ebl + ((size_t)pa << 8) + dl);
    int in = i + 2;
    bool vn = in < i1;
    int sn = 0, pan = 0;
    if (vn){ sn = csrc[in]; pan = cattr[in]; }     // overlap with hv/ev latency
#pragma unroll
    for (int k = 0; k < 8; ++k)
      acc[k] += fmaxf((float)hv[k] + (float)ev[k], 0.f);
    i = in; s = sn; pa = pan; v = vn;
  }
#pragma unroll
  for (int k = 0; k < 8; ++k) acc[k] += __shfl_xor(acc[k], 32);
  if (half == 0){
    float ep = 1.0f + epsv[layer];
    f16x8 hv = *(const f16x8*)(h + (size_t)n*EMB + dl);
    f16x8 o;
#pragma unroll
    for (int k = 0; k < 8; ++k) o[k] = (f16)(acc[k] + ep*(float)hv[k]);
    *(f16x8*)(z + (size_t)n*EMB + dl) = o;
  }
}

// LDS-staged GEMM (round-8 structure, measured 65us): A [M x K] f16 row-major,
// Bt [NCOL x K] f16 (pre-transposed). global_load_lds staging, XOR swizzle.
// FUSEBN: BN1 scale/shift + relu applied in-register AFTER the LDS read of the
// A fragment (A = pre-BN hidden); pad rows (>= NODES) zeroed so downstream BN
// stats stay exact. C f16 pre-BN; column sum/sumsq via f32 atomics.
template<int K, int NCOL, bool FUSEBN>
__global__ __launch_bounds__(256)
void k_gemm(const f16* __restrict__ A, const f16* __restrict__ Bt,
            const f16* __restrict__ bnsc, const f16* __restrict__ bnsh,
            f16* __restrict__ C, float* __restrict__ csum, float* __restrict__ csq){
  __shared__ __align__(16) u16 As[128*64];
  __shared__ __align__(16) u16 Bs[128*64];
  const int tid  = threadIdx.x;
  const int lane = tid & 63;
  const int wid  = tid >> 6;
  const int bm0 = blockIdx.x * 128;
  const int bn0 = blockIdx.y * 128;
  const int wm = (wid >> 1) * 64;
  const int wn = (wid & 1) * 64;

  f32x4 acc[4][4];
#pragma unroll
  for (int m = 0; m < 4; ++m)
#pragma unroll
    for (int n = 0; n < 4; ++n) acc[m][n] = (f32x4){0.f,0.f,0.f,0.f};

  const f16x8 zero8 = {(f16)0.f,(f16)0.f,(f16)0.f,(f16)0.f,
                       (f16)0.f,(f16)0.f,(f16)0.f,(f16)0.f};

  for (int kt = 0; kt < K/64; ++kt){
    __syncthreads();
#pragma unroll
    for (int it = 0; it < 4; ++it){
      int tix = tid + it*256;
      int r = tix >> 3;
      int c = tix & 7;
      int sc = c ^ (r & 7);          // pre-swizzled global source, linear LDS dest
      gload16(A  + (size_t)(bm0 + r)*K + kt*64 + sc*8, (char*)As + tix*16);
      gload16(Bt + (size_t)(bn0 + r)*K + kt*64 + sc*8, (char*)Bs + tix*16);
    }
    __syncthreads();
#pragma unroll
    for (int kk = 0; kk < 2; ++kk){
      f16x8 af[4], bfr[4];
#pragma unroll
      for (int m = 0; m < 4; ++m){
        int row = wm + m*16 + (lane & 15);
        int phys = (kk*4 + (lane >> 4)) ^ (row & 7);
        af[m] = *(const f16x8*)((const char*)As + row*128 + phys*16);
      }
#pragma unroll
      for (int n = 0; n < 4; ++n){
        int row = wn + n*16 + (lane & 15);
        int phys = (kk*4 + (lane >> 4)) ^ (row & 7);
        bfr[n] = *(const f16x8*)((const char*)Bs + row*128 + phys*16);
      }
      if (FUSEBN){
        // logical k of this fragment: kt*64 + (kk*4 + (lane>>4))*8 .. +8
        int kb = kt*64 + (kk*4 + (lane >> 4))*8;
        f16x8 sc = *(const f16x8*)(bnsc + kb);
        f16x8 sh = *(const f16x8*)(bnsh + kb);
#pragma unroll
        for (int m = 0; m < 4; ++m){
          f16x8 t = af[m]*sc + sh;
#pragma unroll
          for (int j = 0; j < 8; ++j) t[j] = (t[j] > (f16)0.f) ? t[j] : (f16)0.f;
          af[m] = (bm0 + wm + m*16 + (lane & 15) < NODES) ? t : zero8;
        }
      }
#pragma unroll
      for (int m = 0; m < 4; ++m)
#pragma unroll
        for (int n = 0; n < 4; ++n)
          acc[m][n] = __builtin_amdgcn_mfma_f32_16x16x32_f16(af[m], bfr[n], acc[m][n], 0, 0, 0);
    }
  }

  const int r0 = (lane >> 4) * 4;
  const int cc = lane & 15;
#pragma unroll
  for (int m = 0; m < 4; ++m)
#pragma unroll
    for (int n = 0; n < 4; ++n)
#pragma unroll
      for (int j = 0; j < 4; ++j){
        int row = bm0 + wm + m*16 + r0 + j;
        int col = bn0 + wn + n*16 + cc;
        C[(size_t)row*NCOL + col] = (f16)acc[m][n][j];
      }
#pragma unroll
  for (int n = 0; n < 4; ++n){
    float s = 0.f, q = 0.f;
#pragma unroll
    for (int m = 0; m < 4; ++m)
#pragma unroll
      for (int j = 0; j < 4; ++j){ float v = acc[m][n][j]; s += v; q += v*v; }
    s += __shfl_xor(s, 16); q += __shfl_xor(q, 16);
    s += __shfl_xor(s, 32); q += __shfl_xor(q, 32);
    if (lane < 16){
      atomicAdd(csum + bn0 + wn + n*16 + cc, s);
      atomicAdd(csq  + bn0 + wn + n*16 + cc, q);
    }
  }
}

__global__ void k_finalize(const float* __restrict__ sum, const float* __restrict__ sumsq,
                           const float* __restrict__ g, const float* __restrict__ be,
                           float* __restrict__ scale, float* __restrict__ shift,
                           f16* __restrict__ scf, f16* __restrict__ shf, int nc){
  int c = blockIdx.x * 256 + threadIdx.x;
  if (c >= nc) return;
  float m = sum[c] * (1.0f / NODES);
  float v = sumsq[c] * (1.0f / NODES) - m*m;
  float sc = rsqrtf(v + BNEPS) * g[c];
  float sh = be[c] - m*sc;
  scale[c] = sc;  shift[c] = sh;
  scf[c] = (f16)sc;  shf[c] = (f16)sh;
}

__global__ void k_apply2(const f16* __restrict__ zp, const float* __restrict__ scale,
                         const float* __restrict__ shift, f16* __restrict__ hout,
                         float* __restrict__ fout, int dorelu){
  int idx = blockIdx.x * 256 + threadIdx.x;       // 8 elems each, NODES*256 total
  int row = idx >> 5;
  int c0  = (idx & 31) * 8;
  if (row >= NODES) return;
  size_t off = (size_t)row * EMB + c0;
  f16x8 v = *(const f16x8*)(zp + off);
  float4 sA = *(const float4*)(scale + c0), sB = *(const float4*)(scale + c0 + 4);
  float4 tA = *(const float4*)(shift + c0), tB = *(const float4*)(shift + c0 + 4);
  float r0 = (float)v[0]*sA.x + tA.x;
  float r1 = (float)v[1]*sA.y + tA.y;
  float r2 = (float)v[2]*sA.z + tA.z;
  float r3 = (float)v[3]*sA.w + tA.w;
  float r4 = (float)v[4]*sB.x + tB.x;
  float r5 = (float)v[5]*sB.y + tB.y;
  float r6 = (float)v[6]*sB.z + tB.z;
  float r7 = (float)v[7]*sB.w + tB.w;
  if (dorelu){
    r0=fmaxf(r0,0.f); r1=fmaxf(r1,0.f); r2=fmaxf(r2,0.f); r3=fmaxf(r3,0.f);
    r4=fmaxf(r4,0.f); r5=fmaxf(r5,0.f); r6=fmaxf(r6,0.f); r7=fmaxf(r7,0.f);
  }
  if (fout){
    float4 f0 = {r0,r1,r2,r3}, f1 = {r4,r5,r6,r7};
    float* q = fout + off;
    *(float4*)q = f0; *(float4*)(q + 4) = f1;
  } else {
    f16x8 o = {(f16)r0,(f16)r1,(f16)r2,(f16)r3,(f16)r4,(f16)r5,(f16)r6,(f16)r7};
    *(f16x8*)(hout + off) = o;
  }
}

// ---------------- launch ----------------

extern "C" void kernel_launch(void* const* d_in, const int* in_sizes, int n_in,
                              void* d_out, int out_size, void* d_ws, size_t ws_size,
                              hipStream_t stream){
  const int*   x    = (const int*)  d_in[0];
  const int*   ei   = (const int*)  d_in[1];
  const int*   ea   = (const int*)  d_in[2];
  const float* aemb = (const float*)d_in[3];
  const float* bemb = (const float*)d_in[4];
  const float* epsv = (const float*)d_in[5];
  const float* W1   = (const float*)d_in[6];
  const float* g1   = (const float*)d_in[8];
  const float* be1  = (const float*)d_in[9];
  const float* W2   = (const float*)d_in[10];
  const float* g2   = (const float*)d_in[12];
  const float* be2  = (const float*)d_in[13];
  float* out = (float*)d_out;

  char* p = (char*)d_ws;
  auto take = [&](size_t bytes){ char* r = p; p += (bytes + 255) & ~(size_t)255; return r; };
  f16* h      = (f16*)take((size_t)NODES*EMB*2);
  f16* z      = (f16*)take((size_t)MPAD*EMB*2);     // reused as GEMM2 output
  f16* hidden = (f16*)take((size_t)MPAD*512*2);
  f16* W1t    = (f16*)take((size_t)5*512*256*2);
  f16* W2t    = (f16*)take((size_t)5*256*512*2);
  f16* eb     = (f16*)take((size_t)5*216*256*2);
  float* stats= (float*)take((size_t)4*512*4);
  float* csum = stats, *csq = stats + 512, *scale = stats + 1024, *shift = stats + 1536;
  f16* scf    = (f16*)take((size_t)512*2);
  f16* shf    = (f16*)take((size_t)512*2);
  int* counts = (int*)take((size_t)NODES*4);
  int* rs     = (int*)take((size_t)(NODES+1)*4);
  int* fill   = (int*)take((size_t)NODES*4);
  int* bsums  = (int*)take((size_t)SCANB*4);
  int* csrc   = (int*)take((size_t)EDGES*4);
  int* cattr  = (int*)take((size_t)EDGES*4);

  k_w1t<<<2560, 256, 0, stream>>>(W1, W1t);
  k_w2t<<<2560, 256, 0, stream>>>(W2, W2t);
  k_ebond<<<5*216, 64, 0, stream>>>(bemb, eb);
  k_atom<<<12500, 256, 0, stream>>>(x, aemb, h);
  hipMemsetAsync(counts, 0, (size_t)NODES*4, stream);
  k_hist<<<EDGES/256, 256, 0, stream>>>(ei + EDGES, counts);
  k_bsum<<<SCANB, 256, 0, stream>>>(counts, bsums);
  k_bscan<<<1, 256, 0, stream>>>(bsums);
  k_fill<<<SCANB, 256, 0, stream>>>(counts, bsums, rs, fill);
  k_scatter<<<EDGES/256, 256, 0, stream>>>(ei, ei + EDGES, ea, fill, csrc, cattr);

  for (int l = 0; l < 5; ++l){
    k_gather<<<MPAD/4, 256, 0, stream>>>(h, eb + (size_t)l*216*256, rs, csrc, cattr, epsv, l, z);
    hipMemsetAsync(stats, 0, 2*512*4, stream);
    k_gemm<256,512,false><<<dim3(MPAD/128, 4), 256, 0, stream>>>(
        z, W1t + (size_t)l*512*256, nullptr, nullptr, hidden, csum, csq);
    k_finalize<<<2, 256, 0, stream>>>(csum, csq, g1 + l*512, be1 + l*512,
                                      scale, shift, scf, shf, 512);
    hipMemsetAsync(stats, 0, 2*512*4, stream);
    k_gemm<512,256,true><<<dim3(MPAD/128, 2), 256, 0, stream>>>(
        hidden, W2t + (size_t)l*256*512, scf, shf, z, csum, csq);
    k_finalize<<<1, 256, 0, stream>>>(csum, csq, g2 + l*256, be2 + l*256,
                                      scale, shift, scf, shf, 256);
    if (l < 4)
      k_apply2<<<NODES*32/256, 256, 0, stream>>>(z, scale, shift, h, nullptr, 1);
    else
      k_apply2<<<NODES*32/256, 256, 0, stream>>>(z, scale, shift, nullptr, out, 0);
  }
}